// Round 1
// baseline (275.297 us; speedup 1.0000x reference)
//
#include <hip/hip_runtime.h>
#include <hip/hip_bf16.h>
#include <cstddef>

#define N_E 400000
#define N_V 50000
#define F_ND 128
#define F_ED 64
#define F_IN 192
#define F_OUT 128
#define BM 64
#define NEG_SLOPE 0.01f
#define BN_EPS 1e-5f

typedef __attribute__((ext_vector_type(8))) short bf16x8;
typedef __attribute__((ext_vector_type(4))) float f32x4;

// ws layout (bytes)
#define PART_OFF   0            // 64 replicas * 256 f32 = 65536 B
#define SCALE_OFF  65536        // 256 f32 (scale[128], shift[128])
#define WT_OFF     66560        // bf16 weights transposed [n][k]
#define WT1_SHORTS 24576        // 128x192
#define WT2_SHORTS 16384        // 128x128
#define META_BYTES 181248
#define H_OFF      181248       // E*128 bf16 = 102,400,000 B

__device__ __forceinline__ unsigned short f2bf(float f) {
  unsigned u = __builtin_bit_cast(unsigned, f);
  u += 0x7fffu + ((u >> 16) & 1u);            // round-to-nearest-even
  return (unsigned short)(u >> 16);
}
__device__ __forceinline__ float bf2f(unsigned short s) {
  return __builtin_bit_cast(float, (unsigned)s << 16);
}
__device__ __forceinline__ float lrelu(float x) {
  return x >= 0.f ? x : NEG_SLOPE * x;
}

// ---- weight staging: copy bf16 Wt[n][K0..K0+KC) -> sW[n][0..KC), padded stride 136
template<int KC>
__device__ __forceinline__ void stageW(const short* __restrict__ srcw, int Kw, int K0,
                                       short* sWl, int tid) {
  const int rowI4 = KC / 8;                    // int4 (8 shorts) per row
  #pragma unroll
  for (int f = tid; f < 128 * rowI4; f += 256) {
    int n = f / rowI4, c8 = f % rowI4;
    *(int4*)(sWl + n * 136 + c8 * 8) = *(const int4*)(srcw + n * Kw + K0 + c8 * 8);
  }
}

// ---- MFMA: D[feat][edge] = Wt x X^T.  A = weights (row=feat-in-tile), B = activations.
template<int KC>
__device__ __forceinline__ void runLayer(const short* sA, int aStride, int koff,
                                         const short* sWl, f32x4* acc, int lane, int w) {
  const int col = lane & 15;                   // edge-in-wave / feat-in-tile selector
  const int kb = (lane >> 4) * 8;
  const short* bp = sA + (w * 16 + col) * aStride + koff + kb;
  const short* ap = sWl + col * 136 + kb;
  #pragma unroll
  for (int kk = 0; kk < KC; kk += 32) {
    bf16x8 bfr = *(const bf16x8*)(bp + kk);
    #pragma unroll
    for (int nt = 0; nt < 8; ++nt) {
      bf16x8 afr = *(const bf16x8*)(ap + nt * (16 * 136) + kk);
      acc[nt] = __builtin_amdgcn_mfma_f32_16x16x32_bf16(afr, bfr, acc[nt], 0, 0, 0);
    }
  }
}

// ---- epilogue: bias + lrelu + pack 4 consecutive feats -> bf16x4 LDS write; reset acc
__device__ __forceinline__ void epiLDS(f32x4* acc, const float* __restrict__ bias,
                                       short* dstL, int dStride, int lane, int w) {
  const int edge = w * 16 + (lane & 15);
  const int fb = (lane >> 4) * 4;
  #pragma unroll
  for (int nt = 0; nt < 8; ++nt) {
    float4 bb = *(const float4*)(bias + nt * 16 + fb);
    float v0 = lrelu(acc[nt][0] + bb.x);
    float v1 = lrelu(acc[nt][1] + bb.y);
    float v2 = lrelu(acc[nt][2] + bb.z);
    float v3 = lrelu(acc[nt][3] + bb.w);
    short4 p;
    p.x = (short)f2bf(v0); p.y = (short)f2bf(v1);
    p.z = (short)f2bf(v2); p.w = (short)f2bf(v3);
    *(short4*)(dstL + edge * dStride + nt * 16 + fb) = p;
    acc[nt] = (f32x4){0.f, 0.f, 0.f, 0.f};
  }
}

template<bool USEWS>
__global__ __launch_bounds__(256, 2) void gnnK(
    const float* __restrict__ nodef, const float* __restrict__ edgef,
    const int* __restrict__ srcI, const int* __restrict__ dstI,
    const float* __restrict__ b1, const float* __restrict__ b2, const float* __restrict__ b3,
    const short* __restrict__ wt, float* __restrict__ partials,
    short* __restrict__ hout, float* fout) {
  __shared__ short sX[64 * 200];   // x (K=192) / h2 reuse; pad->stride 200
  __shared__ short sW[128 * 136];  // transposed weights, K<=128 per stage
  __shared__ short sH[64 * 136];   // h1 / h3
  __shared__ float bSum[128];
  __shared__ float bSq[128];

  const int tid = threadIdx.x;
  const int lane = tid & 63;
  const int w = tid >> 6;
  const int e0 = blockIdx.x * BM;

  if (tid < 128) { bSum[tid] = 0.f; bSq[tid] = 0.f; }

  // stage x: edge-feature part, cols 0..63 (contiguous slab, fully coalesced)
  {
    const float4* ef = (const float4*)edgef + (size_t)e0 * (F_ED / 4);
    #pragma unroll
    for (int i = 0; i < 4; ++i) {
      int f = tid + i * 256;
      int r = f >> 4, c4 = f & 15;
      float4 v = ef[f];
      short4 p;
      p.x = (short)f2bf(v.x); p.y = (short)f2bf(v.y);
      p.z = (short)f2bf(v.z); p.w = (short)f2bf(v.w);
      *(short4*)(sX + r * 200 + c4 * 4) = p;
    }
  }
  // stage x: node gather part (src+dst), cols 64..191; 4 threads per edge row
  {
    int r = tid >> 2, p4 = tid & 3;
    int e = e0 + r;
    const float4* ns = (const float4*)(nodef + (size_t)srcI[e] * F_ND);
    const float4* nd = (const float4*)(nodef + (size_t)dstI[e] * F_ND);
    #pragma unroll
    for (int j = 0; j < 8; ++j) {
      int idx = p4 * 8 + j;
      float4 a = ns[idx], b = nd[idx];
      short4 p;
      p.x = (short)f2bf(a.x + b.x); p.y = (short)f2bf(a.y + b.y);
      p.z = (short)f2bf(a.z + b.z); p.w = (short)f2bf(a.w + b.w);
      *(short4*)(sX + r * 200 + 64 + idx * 4) = p;
    }
  }

  f32x4 acc[8];
  #pragma unroll
  for (int nt = 0; nt < 8; ++nt) acc[nt] = (f32x4){0.f, 0.f, 0.f, 0.f};

  const short* wt1 = wt;
  const short* wt2 = wt + WT1_SHORTS;
  const short* wt3 = wt + WT1_SHORTS + WT2_SHORTS;

  // ---- layer 1 (K=192, split 64+128 so sW fits for 2 blocks/CU) ----
  stageW<64>(wt1, 192, 0, sW, tid);
  __syncthreads();
  runLayer<64>(sX, 200, 0, sW, acc, lane, w);
  __syncthreads();
  stageW<128>(wt1, 192, 64, sW, tid);
  __syncthreads();
  runLayer<128>(sX, 200, 64, sW, acc, lane, w);
  epiLDS(acc, b1, sH, 136, lane, w);           // h1 -> sH
  __syncthreads();
  // ---- layer 2 ----
  stageW<128>(wt2, 128, 0, sW, tid);
  __syncthreads();
  runLayer<128>(sH, 136, 0, sW, acc, lane, w);
  epiLDS(acc, b2, sX, 200, lane, w);           // h2 -> sX (x fully consumed)
  __syncthreads();
  // ---- layer 3 ----
  stageW<128>(wt3, 128, 0, sW, tid);
  __syncthreads();
  runLayer<128>(sX, 200, 0, sW, acc, lane, w);
  epiLDS(acc, b3, sH, 136, lane, w);           // h3 -> sH
  __syncthreads();

  // ---- write h3 (coalesced from LDS) ----
  if (USEWS) {
    int4* dst = (int4*)(hout + (size_t)e0 * F_OUT);
    #pragma unroll
    for (int i = 0; i < 4; ++i) {
      int f = tid + i * 256;
      int r = f >> 4, c8 = f & 15;
      dst[f] = *(const int4*)(sH + r * 136 + c8 * 8);
    }
  } else {
    float4* dst = (float4*)(fout + (size_t)e0 * F_OUT);
    #pragma unroll
    for (int i = 0; i < 8; ++i) {
      int f = tid + i * 256;
      int r = f >> 5, c4 = f & 31;
      short4 s = *(const short4*)(sH + r * 136 + c4 * 4);
      float4 v;
      v.x = bf2f((unsigned short)s.x); v.y = bf2f((unsigned short)s.y);
      v.z = bf2f((unsigned short)s.z); v.w = bf2f((unsigned short)s.w);
      dst[f] = v;
    }
  }

  // ---- per-block BN partial sums from the h3 LDS tile ----
  {
    int c = tid & 127, rh = tid >> 7;
    const short* p = sH + rh * 32 * 136 + c;
    float s = 0.f, s2 = 0.f;
    #pragma unroll
    for (int r = 0; r < 32; ++r) {
      float v = bf2f((unsigned short)p[r * 136]);
      s += v; s2 += v * v;
    }
    atomicAdd(&bSum[c], s);
    atomicAdd(&bSq[c], s2);
  }
  __syncthreads();
  {
    float v = (tid < 128) ? bSum[tid] : bSq[tid - 128];
    atomicAdd(&partials[(blockIdx.x & 63) * 256 + tid], v);
  }
}

__global__ __launch_bounds__(256) void prepK(const float* __restrict__ W1,
                                             const float* __restrict__ W2,
                                             const float* __restrict__ W3,
                                             short* __restrict__ wt,
                                             float* __restrict__ partials) {
  int b = blockIdx.x, t = threadIdx.x;
  if (b < 64) { partials[b * 256 + t] = 0.f; return; }
  int g = (b - 64) * 256 + t;
  for (int f = g; f < 57344; f += 32 * 256) {
    if (f < 24576) {
      int n = f / 192, k = f % 192;
      wt[f] = (short)f2bf(W1[k * 128 + n]);
    } else if (f < 40960) {
      int f2 = f - 24576;
      int n = f2 >> 7, k = f2 & 127;
      wt[24576 + f2] = (short)f2bf(W2[k * 128 + n]);
    } else {
      int f3 = f - 40960;
      int n = f3 >> 7, k = f3 & 127;
      wt[40960 + f3] = (short)f2bf(W3[k * 128 + n]);
    }
  }
}

__global__ __launch_bounds__(256) void statsK(const float* __restrict__ partials,
                                              const float* __restrict__ gamma,
                                              const float* __restrict__ beta,
                                              float* __restrict__ scsh) {
  __shared__ float tmp[256];
  int t = threadIdx.x;
  float a = 0.f;
  #pragma unroll 8
  for (int r = 0; r < 64; ++r) a += partials[r * 256 + t];
  tmp[t] = a;
  __syncthreads();
  if (t < 128) {
    float S = tmp[t], S2 = tmp[t + 128];
    float mean = S / (float)N_E;
    float var = S2 / (float)N_E - mean * mean;   // biased, matches reference
    float inv = rsqrtf(var + BN_EPS);
    float sc = gamma[t] * inv;
    scsh[t] = sc;
    scsh[t + 128] = beta[t] - mean * sc;
  }
}

template<bool USEWS>
__global__ __launch_bounds__(256) void applyK(const short* __restrict__ h,
                                              const float* __restrict__ scsh,
                                              float* out) {
  const int TOT4 = N_E * F_OUT / 4;
  int j0 = blockIdx.x * 256 + threadIdx.x;
  int c4 = j0 & 31;                              // stride divisible by 32 -> constant
  float4 sc = *(const float4*)(scsh + c4 * 4);
  float4 sh = *(const float4*)(scsh + 128 + c4 * 4);
  int stride = gridDim.x * 256;
  for (int j = j0; j < TOT4; j += stride) {
    float4 v;
    if (USEWS) {
      short4 s = *(const short4*)(h + (size_t)j * 4);
      v.x = bf2f((unsigned short)s.x) * sc.x + sh.x;
      v.y = bf2f((unsigned short)s.y) * sc.y + sh.y;
      v.z = bf2f((unsigned short)s.z) * sc.z + sh.z;
      v.w = bf2f((unsigned short)s.w) * sc.w + sh.w;
    } else {
      float4 hv = ((const float4*)out)[j];
      v.x = hv.x * sc.x + sh.x;
      v.y = hv.y * sc.y + sh.y;
      v.z = hv.z * sc.z + sh.z;
      v.w = hv.w * sc.w + sh.w;
    }
    ((float4*)out)[j] = v;
  }
}

extern "C" void kernel_launch(void* const* d_in, const int* in_sizes, int n_in,
                              void* d_out, int out_size, void* d_ws, size_t ws_size,
                              hipStream_t stream) {
  const float* nodef = (const float*)d_in[0];
  const float* edgef = (const float*)d_in[1];
  const int* srcI = (const int*)d_in[2];
  const int* dstI = (const int*)d_in[3];
  const float* W1 = (const float*)d_in[4];
  const float* b1 = (const float*)d_in[5];
  const float* W2 = (const float*)d_in[6];
  const float* b2 = (const float*)d_in[7];
  const float* W3 = (const float*)d_in[8];
  const float* b3 = (const float*)d_in[9];
  const float* gamma = (const float*)d_in[10];
  const float* beta = (const float*)d_in[11];
  float* out = (float*)d_out;
  char* ws = (char*)d_ws;

  float* partials = (float*)(ws + PART_OFF);
  float* scsh = (float*)(ws + SCALE_OFF);
  short* wt = (short*)(ws + WT_OFF);
  short* h = (short*)(ws + H_OFF);
  const bool usews = ws_size >= (size_t)H_OFF + (size_t)N_E * F_OUT * 2;

  prepK<<<96, 256, 0, stream>>>(W1, W2, W3, wt, partials);
  if (usews) {
    gnnK<true><<<N_E / BM, 256, 0, stream>>>(nodef, edgef, srcI, dstI, b1, b2, b3,
                                             wt, partials, h, out);
  } else {
    gnnK<false><<<N_E / BM, 256, 0, stream>>>(nodef, edgef, srcI, dstI, b1, b2, b3,
                                              wt, partials, h, out);
  }
  statsK<<<1, 256, 0, stream>>>(partials, gamma, beta, scsh);
  if (usews) {
    applyK<true><<<2048, 256, 0, stream>>>(h, scsh, out);
  } else {
    applyK<false><<<2048, 256, 0, stream>>>(h, scsh, out);
  }
}

// Round 2
// 211.421 us; speedup vs baseline: 1.3021x; 1.3021x over previous
//
#include <hip/hip_runtime.h>
#include <hip/hip_bf16.h>
#include <cstddef>

#define N_E 400000
#define N_V 50000
#define F_ND 128
#define F_ED 64
#define F_IN 192
#define F_OUT 128
#define BM 64
#define NEG_SLOPE 0.01f
#define BN_EPS 1e-5f

typedef __attribute__((ext_vector_type(8))) short bf16x8;
typedef __attribute__((ext_vector_type(4))) float f32x4;

// ws layout (bytes)
#define PART_OFF   0            // 64 replicas * 256 f32 = 65536 B
#define SCALE_OFF  65536        // 256 f32 (scale[128], shift[128])
#define WT_OFF     66560        // bf16 weights, packed in MFMA A-frag chunks
#define WT1_SHORTS 24576        // L1: 8 tiles x 6 ksteps x 512 shorts
#define WT2_SHORTS 16384        // L2: 8 tiles x 4 ksteps x 512
#define H_OFF      181248       // E*128 bf16 = 102,400,000 B

__device__ __forceinline__ unsigned short f2bf(float f) {
  unsigned u = __builtin_bit_cast(unsigned, f);
  u += 0x7fffu + ((u >> 16) & 1u);            // round-to-nearest-even
  return (unsigned short)(u >> 16);
}
__device__ __forceinline__ float bf2f(unsigned short s) {
  return __builtin_bit_cast(float, (unsigned)s << 16);
}
__device__ __forceinline__ float lrelu(float x) {
  return x >= 0.f ? x : NEG_SLOPE * x;
}

// load A-fragments for this wave's 2 feature tiles, KS k-steps, from packed wt.
// chunk c = (t)*KS + s; each chunk is 64 lanes x 8 shorts, fully coalesced.
template<int KS>
__device__ __forceinline__ void loadA(const short* __restrict__ base, int t0, int lane,
                                      bf16x8* fr) {
  #pragma unroll
  for (int nt = 0; nt < 2; ++nt)
    #pragma unroll
    for (int s = 0; s < KS; ++s)
      fr[nt * KS + s] =
          *(const bf16x8*)(base + ((((t0 + nt) * KS + s) << 9) + lane * 8));
}

// MFMA: D[feat][edge]; A = weights (reg), B = activations (LDS rows = edges).
template<int KS>
__device__ __forceinline__ void runLayer(const short* sA, int aStride,
                                         const bf16x8* fr, f32x4* acc, int lane) {
  const int col = lane & 15;
  const int kb = (lane >> 4) * 8;
  #pragma unroll
  for (int et = 0; et < 4; ++et) {
    const short* bp = sA + (et * 16 + col) * aStride + kb;
    #pragma unroll
    for (int s = 0; s < KS; ++s) {
      bf16x8 bfr = *(const bf16x8*)(bp + s * 32);
      acc[0 * 4 + et] = __builtin_amdgcn_mfma_f32_16x16x32_bf16(fr[0 * KS + s], bfr,
                                                                acc[0 * 4 + et], 0, 0, 0);
      acc[1 * 4 + et] = __builtin_amdgcn_mfma_f32_16x16x32_bf16(fr[1 * KS + s], bfr,
                                                                acc[1 * 4 + et], 0, 0, 0);
    }
  }
}

// epilogue: bias + lrelu -> bf16 short4 into LDS [edge][feat]; reset acc
__device__ __forceinline__ void epi(f32x4* acc, const float* __restrict__ bias, int w,
                                    short* dstL, int dStride, int lane) {
  const int fb = (lane >> 4) * 4;
  const int col = lane & 15;
  #pragma unroll
  for (int nt = 0; nt < 2; ++nt) {
    const int f0 = w * 32 + nt * 16 + fb;
    float4 bb = *(const float4*)(bias + f0);
    #pragma unroll
    for (int et = 0; et < 4; ++et) {
      f32x4 a = acc[nt * 4 + et];
      float v0 = lrelu(a[0] + bb.x), v1 = lrelu(a[1] + bb.y);
      float v2 = lrelu(a[2] + bb.z), v3 = lrelu(a[3] + bb.w);
      short4 p;
      p.x = (short)f2bf(v0); p.y = (short)f2bf(v1);
      p.z = (short)f2bf(v2); p.w = (short)f2bf(v3);
      *(short4*)(dstL + (et * 16 + col) * dStride + f0) = p;
      acc[nt * 4 + et] = (f32x4){0.f, 0.f, 0.f, 0.f};
    }
  }
}

template<bool USEWS>
__global__ __launch_bounds__(256, 3) void gnnK(
    const float* __restrict__ nodef, const float* __restrict__ edgef,
    const int* __restrict__ srcI, const int* __restrict__ dstI,
    const float* __restrict__ b1, const float* __restrict__ b2, const float* __restrict__ b3,
    const short* __restrict__ wt, float* __restrict__ partials,
    short* __restrict__ hout, float* fout) {
  __shared__ short sX[64 * 200];   // x (K=192) / h2; pad->stride 200 (mult of 8)
  __shared__ short sH[64 * 136];   // h1 / h3

  const int tid = threadIdx.x;
  const int lane = tid & 63;
  const int w = tid >> 6;
  const int e0 = blockIdx.x * BM;

  // stage x: edge-feature part, cols 0..63 (contiguous, coalesced)
  {
    const float4* ef = (const float4*)edgef + (size_t)e0 * (F_ED / 4);
    #pragma unroll
    for (int i = 0; i < 4; ++i) {
      int f = tid + i * 256;
      int r = f >> 4, c4 = f & 15;
      float4 v = ef[f];
      short4 p;
      p.x = (short)f2bf(v.x); p.y = (short)f2bf(v.y);
      p.z = (short)f2bf(v.z); p.w = (short)f2bf(v.w);
      *(short4*)(sX + r * 200 + c4 * 4) = p;
    }
  }
  // stage x: node gather (src+dst), cols 64..191; 4 threads per edge row
  {
    int r = tid >> 2, p4 = tid & 3;
    int e = e0 + r;
    const float4* ns = (const float4*)(nodef + (size_t)srcI[e] * F_ND);
    const float4* nd = (const float4*)(nodef + (size_t)dstI[e] * F_ND);
    #pragma unroll
    for (int j = 0; j < 8; ++j) {
      int idx = p4 * 8 + j;
      float4 a = ns[idx], b = nd[idx];
      short4 p;
      p.x = (short)f2bf(a.x + b.x); p.y = (short)f2bf(a.y + b.y);
      p.z = (short)f2bf(a.z + b.z); p.w = (short)f2bf(a.w + b.w);
      *(short4*)(sX + r * 200 + 64 + idx * 4) = p;
    }
  }

  f32x4 acc[8];
  #pragma unroll
  for (int i = 0; i < 8; ++i) acc[i] = (f32x4){0.f, 0.f, 0.f, 0.f};

  const int t0 = w * 2;                        // this wave's feature tiles
  bf16x8 fr1[12];
  loadA<6>(wt, t0, lane, fr1);                 // overlap with staging
  __syncthreads();                             // (1) x ready

  // ---- layer 1 (K=192) ----
  runLayer<6>(sX, 200, fr1, acc, lane);
  bf16x8 fr2[8];
  loadA<4>(wt + WT1_SHORTS, t0, lane, fr2);
  epi(acc, b1, w, sH, 136, lane);              // h1 -> sH
  __syncthreads();                             // (2)

  // ---- layer 2 ----
  runLayer<4>(sH, 136, fr2, acc, lane);
  bf16x8 fr3[8];
  loadA<4>(wt + WT1_SHORTS + WT2_SHORTS, t0, lane, fr3);
  epi(acc, b2, w, sX, 200, lane);              // h2 -> sX (x consumed)
  __syncthreads();                             // (3)

  // ---- layer 3 + register BN partials ----
  runLayer<4>(sX, 200, fr3, acc, lane);
  float sE[8], sQ[8];
  #pragma unroll
  for (int i = 0; i < 8; ++i) { sE[i] = 0.f; sQ[i] = 0.f; }
  {
    const int fb = (lane >> 4) * 4;
    const int col = lane & 15;
    #pragma unroll
    for (int nt = 0; nt < 2; ++nt) {
      const int f0 = w * 32 + nt * 16 + fb;
      float4 bb = *(const float4*)(b3 + f0);
      #pragma unroll
      for (int et = 0; et < 4; ++et) {
        f32x4 a = acc[nt * 4 + et];
        float v0 = lrelu(a[0] + bb.x), v1 = lrelu(a[1] + bb.y);
        float v2 = lrelu(a[2] + bb.z), v3 = lrelu(a[3] + bb.w);
        sE[nt * 4 + 0] += v0; sQ[nt * 4 + 0] += v0 * v0;
        sE[nt * 4 + 1] += v1; sQ[nt * 4 + 1] += v1 * v1;
        sE[nt * 4 + 2] += v2; sQ[nt * 4 + 2] += v2 * v2;
        sE[nt * 4 + 3] += v3; sQ[nt * 4 + 3] += v3 * v3;
        short4 p;
        p.x = (short)f2bf(v0); p.y = (short)f2bf(v1);
        p.z = (short)f2bf(v2); p.w = (short)f2bf(v3);
        *(short4*)(sH + (et * 16 + col) * 136 + f0) = p;
      }
    }
  }
  // butterfly-reduce over edge lanes (low 4 bits of lane)
  #pragma unroll
  for (int m = 1; m <= 8; m <<= 1) {
    #pragma unroll
    for (int i = 0; i < 8; ++i) {
      sE[i] += __shfl_xor(sE[i], m, 64);
      sQ[i] += __shfl_xor(sQ[i], m, 64);
    }
  }
  if ((lane & 15) == 0) {
    float* pp = partials + (blockIdx.x & 63) * 256;
    const int fb = (lane >> 4) * 4;
    #pragma unroll
    for (int nt = 0; nt < 2; ++nt)
      #pragma unroll
      for (int r = 0; r < 4; ++r) {
        int f = w * 32 + nt * 16 + fb + r;
        atomicAdd(&pp[f], sE[nt * 4 + r]);
        atomicAdd(&pp[128 + f], sQ[nt * 4 + r]);
      }
  }
  __syncthreads();                             // (4) h3 ready in sH

  // ---- write h3 (coalesced from LDS) ----
  if (USEWS) {
    int4* dst = (int4*)(hout + (size_t)e0 * F_OUT);
    #pragma unroll
    for (int i = 0; i < 4; ++i) {
      int f = tid + i * 256;
      int r = f >> 4, c8 = f & 15;
      dst[f] = *(const int4*)(sH + r * 136 + c8 * 8);
    }
  } else {
    float4* dst = (float4*)(fout + (size_t)e0 * F_OUT);
    #pragma unroll
    for (int i = 0; i < 8; ++i) {
      int f = tid + i * 256;
      int r = f >> 5, c4 = f & 31;
      short4 s = *(const short4*)(sH + r * 136 + c4 * 4);
      float4 v;
      v.x = bf2f((unsigned short)s.x); v.y = bf2f((unsigned short)s.y);
      v.z = bf2f((unsigned short)s.z); v.w = bf2f((unsigned short)s.w);
      dst[f] = v;
    }
  }
}

// pack weights into per-frag chunk order: layer L, tile t, kstep s ->
// chunk of 64 lanes x 8 shorts; lane l holds W[k = s*32+(l>>4)*8+j][n = t*16+(l&15)]
__global__ __launch_bounds__(256) void prepK(const float* __restrict__ W1,
                                             const float* __restrict__ W2,
                                             const float* __restrict__ W3,
                                             short* __restrict__ wt,
                                             float* __restrict__ partials) {
  int b = blockIdx.x, t = threadIdx.x;
  if (b < 64) { partials[b * 256 + t] = 0.f; return; }
  int g = (b - 64) * 256 + t;
  for (int f = g; f < 57344; f += 32 * 256) {
    float val;
    if (f < 24576) {
      int c = f >> 9, r = f & 511;
      int l = r >> 3, j = r & 7;
      int tt = c / 6, s = c % 6;
      int n = tt * 16 + (l & 15);
      int k = s * 32 + (l >> 4) * 8 + j;
      val = W1[k * 128 + n];
    } else if (f < 40960) {
      int f2 = f - 24576;
      int c = f2 >> 9, r = f2 & 511;
      int l = r >> 3, j = r & 7;
      int tt = c >> 2, s = c & 3;
      int n = tt * 16 + (l & 15);
      int k = s * 32 + (l >> 4) * 8 + j;
      val = W2[k * 128 + n];
    } else {
      int f3 = f - 40960;
      int c = f3 >> 9, r = f3 & 511;
      int l = r >> 3, j = r & 7;
      int tt = c >> 2, s = c & 3;
      int n = tt * 16 + (l & 15);
      int k = s * 32 + (l >> 4) * 8 + j;
      val = W3[k * 128 + n];
    }
    wt[f] = (short)f2bf(val);
  }
}

__global__ __launch_bounds__(256) void statsK(const float* __restrict__ partials,
                                              const float* __restrict__ gamma,
                                              const float* __restrict__ beta,
                                              float* __restrict__ scsh) {
  __shared__ float tmp[256];
  int t = threadIdx.x;
  float a = 0.f;
  #pragma unroll 8
  for (int r = 0; r < 64; ++r) a += partials[r * 256 + t];
  tmp[t] = a;
  __syncthreads();
  if (t < 128) {
    float S = tmp[t], S2 = tmp[t + 128];
    float mean = S / (float)N_E;
    float var = S2 / (float)N_E - mean * mean;   // biased, matches reference
    float inv = rsqrtf(var + BN_EPS);
    float sc = gamma[t] * inv;
    scsh[t] = sc;
    scsh[t + 128] = beta[t] - mean * sc;
  }
}

template<bool USEWS>
__global__ __launch_bounds__(256) void applyK(const short* __restrict__ h,
                                              const float* __restrict__ scsh,
                                              float* out) {
  const int TOT4 = N_E * F_OUT / 4;
  int j0 = blockIdx.x * 256 + threadIdx.x;
  int c4 = j0 & 31;
  float4 sc = *(const float4*)(scsh + c4 * 4);
  float4 sh = *(const float4*)(scsh + 128 + c4 * 4);
  int stride = gridDim.x * 256;
  for (int j = j0; j < TOT4; j += stride) {
    float4 v;
    if (USEWS) {
      short4 s = *(const short4*)(h + (size_t)j * 4);
      v.x = bf2f((unsigned short)s.x) * sc.x + sh.x;
      v.y = bf2f((unsigned short)s.y) * sc.y + sh.y;
      v.z = bf2f((unsigned short)s.z) * sc.z + sh.z;
      v.w = bf2f((unsigned short)s.w) * sc.w + sh.w;
    } else {
      float4 hv = ((const float4*)out)[j];
      v.x = hv.x * sc.x + sh.x;
      v.y = hv.y * sc.y + sh.y;
      v.z = hv.z * sc.z + sh.z;
      v.w = hv.w * sc.w + sh.w;
    }
    ((float4*)out)[j] = v;
  }
}

extern "C" void kernel_launch(void* const* d_in, const int* in_sizes, int n_in,
                              void* d_out, int out_size, void* d_ws, size_t ws_size,
                              hipStream_t stream) {
  const float* nodef = (const float*)d_in[0];
  const float* edgef = (const float*)d_in[1];
  const int* srcI = (const int*)d_in[2];
  const int* dstI = (const int*)d_in[3];
  const float* W1 = (const float*)d_in[4];
  const float* b1 = (const float*)d_in[5];
  const float* W2 = (const float*)d_in[6];
  const float* b2 = (const float*)d_in[7];
  const float* W3 = (const float*)d_in[8];
  const float* b3 = (const float*)d_in[9];
  const float* gamma = (const float*)d_in[10];
  const float* beta = (const float*)d_in[11];
  float* out = (float*)d_out;
  char* ws = (char*)d_ws;

  float* partials = (float*)(ws + PART_OFF);
  float* scsh = (float*)(ws + SCALE_OFF);
  short* wt = (short*)(ws + WT_OFF);
  short* h = (short*)(ws + H_OFF);
  const bool usews = ws_size >= (size_t)H_OFF + (size_t)N_E * F_OUT * 2;

  prepK<<<96, 256, 0, stream>>>(W1, W2, W3, wt, partials);
  if (usews) {
    gnnK<true><<<N_E / BM, 256, 0, stream>>>(nodef, edgef, srcI, dstI, b1, b2, b3,
                                             wt, partials, h, out);
  } else {
    gnnK<false><<<N_E / BM, 256, 0, stream>>>(nodef, edgef, srcI, dstI, b1, b2, b3,
                                              wt, partials, h, out);
  }
  statsK<<<1, 256, 0, stream>>>(partials, gamma, beta, scsh);
  if (usews) {
    applyK<true><<<2048, 256, 0, stream>>>(h, scsh, out);
  } else {
    applyK<false><<<2048, 256, 0, stream>>>(h, scsh, out);
  }
}